// Round 2
// baseline (18533.730 us; speedup 1.0000x reference)
//
#include <hip/hip_runtime.h>
#include <math.h>

#define BB 64
#define SS 512
#define EE 512
#define HH 1024
#define NWG 256

// ws layout:
//   INP  [S][H][B] float              (128 MiB)  inp[t][j][b]
//   h0,h1,hsel,lin : float4 [H/4][B]  (256 KiB each)  h[k4][b] quad = k=4k4..+3
//   barcnt : unsigned (zeroed each launch)

#define DOT4(acc, u, v) acc += (u).x*(v).x + (u).y*(v).y + (u).z*(v).z + (u).w*(v).w

__global__ __launch_bounds__(512) void gemm1_kernel(
    const int* __restrict__ x, const float* __restrict__ emb,
    const float* __restrict__ Wi, const float* __restrict__ bi,
    float* __restrict__ INP)
{
    int t    = blockIdx.y;
    int lane = threadIdx.x & 63;                                   // batch b
    int wave = __builtin_amdgcn_readfirstlane(threadIdx.x >> 6);   // 0..7
    int j4   = blockIdx.x * 8 + wave;                              // 0..255

    int row = x[lane * SS + t];
    const float4* e  = reinterpret_cast<const float4*>(emb + (size_t)row * EE);
    const float4* w0 = reinterpret_cast<const float4*>(Wi + (size_t)(j4*4+0) * EE);
    const float4* w1 = reinterpret_cast<const float4*>(Wi + (size_t)(j4*4+1) * EE);
    const float4* w2 = reinterpret_cast<const float4*>(Wi + (size_t)(j4*4+2) * EE);
    const float4* w3 = reinterpret_cast<const float4*>(Wi + (size_t)(j4*4+3) * EE);

    float a0 = 0.f, a1 = 0.f, a2 = 0.f, a3 = 0.f;
    #pragma unroll 8
    for (int k4 = 0; k4 < EE/4; ++k4) {
        float4 ev = e[k4];
        float4 w;
        w = w0[k4]; DOT4(a0, ev, w);
        w = w1[k4]; DOT4(a1, ev, w);
        w = w2[k4]; DOT4(a2, ev, w);
        w = w3[k4]; DOT4(a3, ev, w);
    }
    float4 bv = *reinterpret_cast<const float4*>(bi + j4*4);
    size_t base = ((size_t)t * HH + j4*4) * 64 + lane;
    INP[base + 0*64] = fmaxf(a0 + bv.x, 0.f);
    INP[base + 1*64] = fmaxf(a1 + bv.y, 0.f);
    INP[base + 2*64] = fmaxf(a2 + bv.z, 0.f);
    INP[base + 3*64] = fmaxf(a3 + bv.w, 0.f);
}

__device__ __forceinline__ void grid_bar(unsigned* cnt, unsigned target) {
    __syncthreads();
    if (threadIdx.x == 0) {
        __threadfence();                 // agent release: drain + L2 writeback
        atomicAdd(cnt, 1u);
        while (__hip_atomic_load(cnt, __ATOMIC_RELAXED, __HIP_MEMORY_SCOPE_AGENT) < target)
            __builtin_amdgcn_s_sleep(2);
        __threadfence();                 // agent acquire: L1/L2 invalidate
    }
    __syncthreads();
}

__global__ __launch_bounds__(1024, 4) void seq_kernel(
    const float* __restrict__ INP,
    const float* __restrict__ Wf, const float* __restrict__ bfv,
    const float* __restrict__ Wh, const float* __restrict__ bhv,
    const float* __restrict__ Wo, const float* __restrict__ bov,
    const float* __restrict__ Wlin, const float* __restrict__ blv,
    const int* __restrict__ lengths,
    float4* __restrict__ h0, float4* __restrict__ h1,
    float4* __restrict__ hsel, float4* __restrict__ lin,
    float* __restrict__ out, unsigned* __restrict__ barcnt)
{
    __shared__ float pf[16][4][64];
    __shared__ float ph[16][4][64];

    const int tid  = threadIdx.x;
    const int lane = tid & 63;
    const int kq   = __builtin_amdgcn_readfirstlane(tid >> 6);   // 0..15 K-split
    const int jg   = blockIdx.x;                                 // col quad 0..255

    // weight row pointers for this wave's K-window (floats [kq*64, kq*64+64))
    const float4* wf0 = (const float4*)Wf + (size_t)(jg*4+0)*256 + kq*16;
    const float4* wf1 = (const float4*)Wf + (size_t)(jg*4+1)*256 + kq*16;
    const float4* wf2 = (const float4*)Wf + (size_t)(jg*4+2)*256 + kq*16;
    const float4* wf3 = (const float4*)Wf + (size_t)(jg*4+3)*256 + kq*16;
    const float4* wh0 = (const float4*)Wh + (size_t)(jg*4+0)*256 + kq*16;
    const float4* wh1 = (const float4*)Wh + (size_t)(jg*4+1)*256 + kq*16;
    const float4* wh2 = (const float4*)Wh + (size_t)(jg*4+2)*256 + kq*16;
    const float4* wh3 = (const float4*)Wh + (size_t)(jg*4+3)*256 + kq*16;

    // finish-phase per-thread constants (threads 0..255: c = tid>>6, b = tid&63)
    const int fc = tid >> 6;          // also wave id; valid as col only when tid<256
    const int fb = tid & 63;
    float bf_c = 0.f, bh_c = 0.f, bo_c = 0.f;
    int   mylen = 0;
    if (tid < 256) {
        bf_c = bfv[jg*4+fc]; bh_c = bhv[jg*4+fc]; bo_c = bov[jg*4+fc];
        mylen = lengths[fb];
    }

    for (int t = 0; t < SS; ++t) {
        const float4* hin  = (t & 1) ? h1 : h0;
        float4*       hout = (t & 1) ? h0 : h1;
        const float4* hp   = hin + kq*16*64;

        float f0=0.f,f1=0.f,f2=0.f,f3=0.f, g0=0.f,g1=0.f,g2=0.f,g3=0.f;
        #pragma unroll 8
        for (int k4 = 0; k4 < 16; ++k4) {
            float4 hv = hp[k4*64 + lane];
            float4 w;
            w = wf0[k4]; DOT4(f0, hv, w);
            w = wf1[k4]; DOT4(f1, hv, w);
            w = wf2[k4]; DOT4(f2, hv, w);
            w = wf3[k4]; DOT4(f3, hv, w);
            w = wh0[k4]; DOT4(g0, hv, w);
            w = wh1[k4]; DOT4(g1, hv, w);
            w = wh2[k4]; DOT4(g2, hv, w);
            w = wh3[k4]; DOT4(g3, hv, w);
        }
        pf[kq][0][lane]=f0; pf[kq][1][lane]=f1; pf[kq][2][lane]=f2; pf[kq][3][lane]=f3;
        ph[kq][0][lane]=g0; ph[kq][1][lane]=g1; ph[kq][2][lane]=g2; ph[kq][3][lane]=g3;
        __syncthreads();

        if (tid < 256) {
            float iv = INP[((size_t)t*HH + jg*4 + fc)*64 + fb];
            float sf = bf_c, sh = bh_c;
            #pragma unroll
            for (int q = 0; q < 16; ++q) { sf += pf[q][fc][fb]; sh += ph[q][fc][fb]; }
            float hn = 1.f/(1.f+expf(-sf)) + tanhf(sh)*iv;
            ((float*)(hout + jg*64 + fb))[fc] = hn;
            if (t == mylen - 1) ((float*)(hsel + jg*64 + fb))[fc] = hn;
        }
        grid_bar(barcnt, (unsigned)(t+1)*NWG);
    }

    // ---- output projection on hsel (same tiling) ----
    {
        const float4* wo0 = (const float4*)Wo + (size_t)(jg*4+0)*256 + kq*16;
        const float4* wo1 = (const float4*)Wo + (size_t)(jg*4+1)*256 + kq*16;
        const float4* wo2 = (const float4*)Wo + (size_t)(jg*4+2)*256 + kq*16;
        const float4* wo3 = (const float4*)Wo + (size_t)(jg*4+3)*256 + kq*16;
        const float4* hp  = hsel + kq*16*64;
        float a0=0.f,a1=0.f,a2=0.f,a3=0.f;
        #pragma unroll 8
        for (int k4 = 0; k4 < 16; ++k4) {
            float4 hv = hp[k4*64 + lane];
            float4 w;
            w = wo0[k4]; DOT4(a0, hv, w);
            w = wo1[k4]; DOT4(a1, hv, w);
            w = wo2[k4]; DOT4(a2, hv, w);
            w = wo3[k4]; DOT4(a3, hv, w);
        }
        pf[kq][0][lane]=a0; pf[kq][1][lane]=a1; pf[kq][2][lane]=a2; pf[kq][3][lane]=a3;
        __syncthreads();
        if (tid < 256) {
            float s = bo_c;
            #pragma unroll
            for (int q = 0; q < 16; ++q) s += pf[q][fc][fb];
            ((float*)(lin + jg*64 + fb))[fc] = s;
        }
    }
    grid_bar(barcnt, (unsigned)(SS+1)*NWG);

    // ---- final linear + log_softmax (one wave of WG 0) ----
    if (jg == 0 && tid < 64) {
        int b = tid;
        float l0 = blv[0], l1 = blv[1];
        const float4* w0 = (const float4*)Wlin;
        const float4* w1 = (const float4*)Wlin + 256;
        #pragma unroll 4
        for (int j4 = 0; j4 < 256; ++j4) {
            float4 v = lin[j4*64 + b];
            float4 wa = w0[j4], wb = w1[j4];
            DOT4(l0, v, wa);
            DOT4(l1, v, wb);
        }
        float m   = fmaxf(l0, l1);
        float lse = m + logf(expf(l0 - m) + expf(l1 - m));
        out[b*2 + 0] = l0 - lse;
        out[b*2 + 1] = l1 - lse;
    }
}

extern "C" void kernel_launch(void* const* d_in, const int* in_sizes, int n_in,
                              void* d_out, int out_size, void* d_ws, size_t ws_size,
                              hipStream_t stream) {
    (void)in_sizes; (void)n_in; (void)out_size; (void)ws_size;
    const int*   x       = (const int*)  d_in[0];
    const int*   lengths = (const int*)  d_in[1];
    const float* emb     = (const float*)d_in[2];
    const float* Wi      = (const float*)d_in[3];
    const float* bi      = (const float*)d_in[4];
    const float* Wf      = (const float*)d_in[5];
    const float* bf      = (const float*)d_in[6];
    const float* Wh      = (const float*)d_in[7];
    const float* bh      = (const float*)d_in[8];
    const float* Wo      = (const float*)d_in[9];
    const float* bo      = (const float*)d_in[10];
    const float* Wlin    = (const float*)d_in[11];
    const float* blin    = (const float*)d_in[12];
    float* out = (float*)d_out;

    char* ws = (char*)d_ws;
    const size_t INP_BYTES = (size_t)SS * HH * 64 * sizeof(float); // 128 MiB
    float*    INP    = (float*)ws;
    float4*   h0     = (float4*)(ws + INP_BYTES);
    float4*   h1     = h0 + 256*64;
    float4*   hsel   = h1 + 256*64;
    float4*   lin    = hsel + 256*64;
    unsigned* barcnt = (unsigned*)(lin + 256*64);

    // h0 must start zeroed; barcnt must start at 0 (ws is poisoned 0xAA each call)
    hipMemsetAsync(h0, 0, 256*64*sizeof(float4), stream);
    hipMemsetAsync(barcnt, 0, 64, stream);

    gemm1_kernel<<<dim3(32, 512), 512, 0, stream>>>(x, emb, Wi, bi, INP);

    void* args[] = {&INP, &Wf, &bf, &Wh, &bh, &Wo, &bo, &Wlin, &blin,
                    &lengths, &h0, &h1, &hsel, &lin, &out, &barcnt};
    hipLaunchCooperativeKernel((const void*)seq_kernel, dim3(NWG), dim3(1024),
                               args, 0, stream);
}